// Round 18
// baseline (203.745 us; speedup 1.0000x reference)
//
#include <hip/hip_runtime.h>
#include <math.h>

namespace {

constexpr int Bn = 2, Hn = 128, Wn = 128, Cn = 256, Vn = 64;
constexpr int VT_W = 144;                 // padded width (16B-aligned rows): cols -2..141

typedef __fp16 fp16x2 __attribute__((ext_vector_type(2)));
typedef __fp16 fp16x4 __attribute__((ext_vector_type(4)));
typedef _Float16 half8v __attribute__((ext_vector_type(8)));
typedef float f32x4 __attribute__((ext_vector_type(4)));
union H8 { half8v v; fp16x2 h2[4]; };

constexpr size_t N_MAIN = (size_t)Bn * Hn * Wn * Cn;   // 8,388,608
constexpr size_t N_VT   = (size_t)Bn * Hn * Vn * VT_W; // 2,359,296
constexpr size_t OFF_AH = 0;
constexpr size_t OFF_AL = OFF_AH + N_MAIN * 2;
constexpr size_t OFF_BH = OFF_AL + N_MAIN * 2;
constexpr size_t OFF_BL = OFF_BH + N_MAIN * 2;
constexpr size_t OFF_VT = OFF_BL + N_MAIN * 2;
constexpr size_t WS_NEED = OFF_VT + N_VT * 2;          // ~71.8 MB

__device__ __forceinline__ void load8(float* r, const float* p) {
    float4 a = *(const float4*)(p);
    float4 b = *(const float4*)(p + 4);
    r[0]=a.x; r[1]=a.y; r[2]=a.z; r[3]=a.w;
    r[4]=b.x; r[5]=b.y; r[6]=b.z; r[7]=b.w;
}

__device__ __forceinline__ void cvt_split(const float* x, half8v& hi, half8v& lo) {
    H8 h, l;
    #pragma unroll
    for (int i = 0; i < 4; ++i) {
        fp16x2 hh = __builtin_amdgcn_cvt_pkrtz(x[2*i], x[2*i+1]);
        h.h2[i] = hh;
        l.h2[i] = __builtin_amdgcn_cvt_pkrtz(x[2*i]   - (float)hh[0],
                                             x[2*i+1] - (float)hh[1]);
    }
    hi = h.v; lo = l.v;
}

__device__ __forceinline__ half8v cvt_h8(const float* x) {
    H8 h;
    #pragma unroll
    for (int i = 0; i < 4; ++i) h.h2[i] = __builtin_amdgcn_cvt_pkrtz(x[2*i], x[2*i+1]);
    return h.v;
}

__device__ __forceinline__ f32x4 mfma16(half8v a, half8v b, f32x4 c) {
    return __builtin_amdgcn_mfma_f32_16x16x32_f16(a, b, c, 0, 0, 0);
}

__device__ __forceinline__ int clampi(int v, int lo, int hi) {
    return v < lo ? lo : (v > hi ? hi : v);
}

// ---------------- prepass 1: fp32 -> fp16 hi/lo planes for main & ref ------
__global__ __launch_bounds__(256)
void prep_split(const float* __restrict__ mainp, const float* __restrict__ refp,
                _Float16* __restrict__ ah, _Float16* __restrict__ al,
                _Float16* __restrict__ bh, _Float16* __restrict__ bl)
{
    const size_t i = ((size_t)blockIdx.x * 256 + threadIdx.x) * 8;  // exact cover
    float r[8];
    half8v hi, lo;
    load8(r, mainp + i);
    cvt_split(r, hi, lo);
    *(half8v*)(ah + i) = hi;
    *(half8v*)(al + i) = lo;
    load8(r, refp + i);
    cvt_split(r, hi, lo);
    *(half8v*)(bh + i) = hi;
    *(half8v*)(bl + i) = lo;
}

// ---------------- prepass 2: refv -> transposed padded fp16 Vt -------------
// Vt[b][h][v][wp], wp = w + 2, width 144 (pads zeroed).
__global__ __launch_bounds__(256)
void prep_vt(const float* __restrict__ refv, _Float16* __restrict__ vt)
{
    const size_t o = (size_t)blockIdx.x * 256 + threadIdx.x;  // one per 4 outputs
    const int w4 = (int)(o % (VT_W / 4));
    const size_t rest = o / (VT_W / 4);
    const int v = (int)(rest % Vn);
    const size_t bh_ = rest / Vn;                 // b*Hn + h
    fp16x4 out;
    #pragma unroll
    for (int j = 0; j < 4; ++j) {
        const int w = w4 * 4 + j - 2;
        float val = 0.f;
        if ((unsigned)w < (unsigned)Wn) val = refv[(bh_ * Wn + w) * Vn + v];
        out[j] = (__fp16)val;
    }
    *(fp16x4*)(vt + (bh_ * Vn + v) * VT_W + w4 * 4) = out;
}

// ---------------- main: MFMA attention from fp16 planes --------------------
// Wave = 16 px; block = 4 waves; grid 512 XCD-banded. Scores: split fp16
// (3 MFMA/tile/kk) from Bh/Bl planes — zero conversion VALU. PV: A = Vt
// contiguous 16B frags, B = banded W from LDS. Layouts per R17 (verified).
__global__ __launch_bounds__(256)
void attn_mfma(const _Float16* __restrict__ ah, const _Float16* __restrict__ al,
               const _Float16* __restrict__ bh, const _Float16* __restrict__ bl,
               const _Float16* __restrict__ vt,
               const float* __restrict__ mainv, float* __restrict__ outp)
{
    const int l  = threadIdx.x & 63;
    const int wv = threadIdx.x >> 6;
    const int ln = l & 15;
    const int kg = l >> 4;

    const int bid = blockIdx.x;
    const int wid = ((bid & 7) << 6) | (bid >> 3);
    const int strip = wid & 1;
    const int h = (wid >> 1) & 127;
    const int b = wid >> 8;
    const int w0 = strip * 64 + wv * 16;

    __shared__ float SW[4][16][28];
    float (*sw)[28] = SW[wv];

    // ---- phase 1: A fragments from planes + self (fp32 from hi+lo) ----
    half8v Ah[8], Al[8];
    float self = 0.f;
    {
        const size_t abase = ((size_t)((b*Hn + h)*Wn) + w0 + ln) * Cn + kg*8;
        #pragma unroll
        for (int kk = 0; kk < 8; ++kk) {
            Ah[kk] = *(const half8v*)(ah + abase + kk*32);
            Al[kk] = *(const half8v*)(al + abase + kk*32);
            #pragma unroll
            for (int j = 0; j < 8; ++j) {
                const float x = (float)Ah[kk][j] + (float)Al[kk][j];
                self = fmaf(x, x, self);
            }
        }
        self += __shfl_xor(self, 16);
        self += __shfl_xor(self, 32);
    }

    // ---- phase 2: score MFMAs ----
    #pragma unroll 1
    for (int di = 0; di < 5; ++di) {
        const int hhc = clampi(h + di - 2, 0, 127);
        const size_t rb = (size_t)((b*Hn + hhc)*Wn);
        const int c0c = clampi(w0 - 2 + ln, 0, 127);
        const int c1c = clampi(w0 + 14 + ln, 0, 127);
        const _Float16* p0h = bh + (rb + c0c)*Cn + kg*8;
        const _Float16* p0l = bl + (rb + c0c)*Cn + kg*8;
        const _Float16* p1h = bh + (rb + c1c)*Cn + kg*8;
        const _Float16* p1l = bl + (rb + c1c)*Cn + kg*8;
        f32x4 a0{0.f,0.f,0.f,0.f}, b0{0.f,0.f,0.f,0.f};
        f32x4 a1{0.f,0.f,0.f,0.f}, b1{0.f,0.f,0.f,0.f};
        #pragma unroll 2
        for (int kk = 0; kk < 8; ++kk) {
            const half8v B0h = *(const half8v*)(p0h + kk*32);
            const half8v B0l = *(const half8v*)(p0l + kk*32);
            const half8v B1h = *(const half8v*)(p1h + kk*32);
            const half8v B1l = *(const half8v*)(p1l + kk*32);
            a0 = mfma16(Ah[kk], B0h, a0);
            b0 = mfma16(Al[kk], B0h, b0);
            b0 = mfma16(Ah[kk], B0l, b0);
            a1 = mfma16(Ah[kk], B1h, a1);
            b1 = mfma16(Al[kk], B1h, b1);
            b1 = mfma16(Ah[kk], B1l, b1);
        }
        #pragma unroll
        for (int reg = 0; reg < 4; ++reg) {
            const int m = kg*4 + reg;
            const int d0 = ln - m;
            if (d0 >= 0 && d0 <= 4) sw[m][di*5 + d0] = a0[reg] + b0[reg];
            const int d1 = ln + 16 - m;
            if (d1 >= 0 && d1 <= 4) sw[m][di*5 + d1] = a1[reg] + b1[reg];
        }
    }

    // ---- phase 3: softmax (lane owns px=ln; kg-redundant) ----
    {
        float s[25];
        #pragma unroll
        for (int k = 0; k < 25; ++k) s[k] = sw[ln][k];
        const int pxg = w0 + ln;
        float mx = self;
        #pragma unroll
        for (int di = 0; di < 5; ++di) {
            const bool rok = (unsigned)(h + di - 2) < 128u;
            #pragma unroll
            for (int d = 0; d < 5; ++d) {
                const bool ok = rok && (unsigned)(pxg + d - 2) < 128u;
                s[di*5+d] = ok ? s[di*5+d] : 0.f;
                mx = fmaxf(mx, s[di*5+d]);
            }
        }
        float den = __expf(self - mx);
        const float wself = den;
        #pragma unroll
        for (int di = 0; di < 5; ++di) {
            const bool rok = (unsigned)(h + di - 2) < 128u;
            #pragma unroll
            for (int d = 0; d < 5; ++d) {
                const float e = __expf(s[di*5+d] - mx);
                den += e;                              // padded slots keep exp(0-mx)
                const bool ok = rok && (unsigned)(pxg + d - 2) < 128u;
                s[di*5+d] = ok ? e : 0.f;              // but contribute 0 value
            }
        }
        #pragma unroll
        for (int k = 0; k < 25; ++k) sw[ln][k] = s[k];
        sw[ln][25] = wself;
        sw[ln][26] = 1.f / den;
    }

    // ---- phase 4: PV MFMAs — A = Vt (contiguous), B = banded W ----
    f32x4 cv0{0.f,0.f,0.f,0.f}, cv1{0.f,0.f,0.f,0.f};
    f32x4 cv2{0.f,0.f,0.f,0.f}, cv3{0.f,0.f,0.f,0.f};
    #pragma unroll 1
    for (int di = 0; di < 5; ++di) {
        float wr[8];
        #pragma unroll
        for (int j = 0; j < 8; ++j) {
            const int d  = kg*8 + j - ln;
            const int dc = clampi(d, 0, 4);
            const float wv_ = sw[ln][di*5 + dc];
            wr[j] = (d == dc) ? wv_ : 0.f;
        }
        const half8v Wf = cvt_h8(wr);

        const int hhc = clampi(h + di - 2, 0, 127);
        const _Float16* vrow = vt + ((size_t)(b*Hn + hhc) * Vn) * VT_W + (w0 + kg*8);
        const half8v V0 = *(const half8v*)(vrow + (0*16 + ln) * VT_W);
        const half8v V1 = *(const half8v*)(vrow + (1*16 + ln) * VT_W);
        const half8v V2 = *(const half8v*)(vrow + (2*16 + ln) * VT_W);
        const half8v V3 = *(const half8v*)(vrow + (3*16 + ln) * VT_W);
        cv0 = mfma16(V0, Wf, cv0);
        cv1 = mfma16(V1, Wf, cv1);
        cv2 = mfma16(V2, Wf, cv2);
        cv3 = mfma16(V3, Wf, cv3);
    }

    // ---- epilogue: lane holds O[px=ln][v = t*16 + kg*4 + reg] ----
    {
        const int pxg = w0 + ln;
        const float ws  = sw[ln][25];
        const float inv = sw[ln][26];
        const size_t pbase = ((size_t)((b*Hn + h)*Wn) + pxg) * Vn;
        const float* mvp = mainv + pbase;
        float* op = outp + pbase;
        #pragma unroll
        for (int t = 0; t < 4; ++t) {
            const f32x4 cv = (t==0) ? cv0 : (t==1) ? cv1 : (t==2) ? cv2 : cv3;
            float4 mv = *(const float4*)(mvp + t*16 + kg*4);
            float4 o;
            o.x = (cv[0] + ws * mv.x) * inv;
            o.y = (cv[1] + ws * mv.y) * inv;
            o.z = (cv[2] + ws * mv.z) * inv;
            o.w = (cv[3] + ws * mv.w) * inv;
            *(float4*)(op + t*16 + kg*4) = o;
        }
    }
}

// ---------------- fallback: R12 proven kernel (35.5us) ---------------------
template <int CTRL>
__device__ __forceinline__ float row_add(float v) {
    int sh = __builtin_amdgcn_update_dpp(0, __float_as_int(v), CTRL, 0xF, 0xF, true);
    return v + __int_as_float(sh);
}
__device__ __forceinline__ float split_reduce(float v) {
    v = row_add<0xB1>(v);
    v = row_add<0x4E>(v);
    v = row_add<0x124>(v);
    v = row_add<0x128>(v);
    v += __int_as_float(__builtin_amdgcn_ds_swizzle(__float_as_int(v), 0x401F));
    return v;
}

__global__ __launch_bounds__(256)
void fallback_kernel(const float* __restrict__ mainp, const float* __restrict__ mainv,
                     const float* __restrict__ refp, const float* __restrict__ refv,
                     float* __restrict__ outp)
{
    const int t = threadIdx.x;
    const int s = t & 31;
    const int g = t >> 5;
    const int blk = blockIdx.x;
    const int seg = blk & 7;
    const int h   = (blk >> 3) & (Hn - 1);
    const int b   = blk >> 10;
    const int w0  = seg * 16 + g * 2;
    const int rowbase = b * Hn + h;

    float m0[8], m1[8];
    const float* mp = mainp + ((size_t)rowbase * Wn + w0) * Cn + s * 8;
    load8(m0, mp);
    load8(m1, mp + Cn);

    float self0 = 0.f, self1 = 0.f;
    #pragma unroll
    for (int c = 0; c < 8; ++c) {
        self0 = fmaf(m0[c], m0[c], self0);
        self1 = fmaf(m1[c], m1[c], self1);
    }
    self0 = split_reduce(self0);
    self1 = split_reduce(self1);

    float mx0 = self0, mx1 = self1, den0 = 1.f, den1 = 1.f;
    float acc0[2], acc1[2];
    {
        const float* mvp = mainv + ((size_t)rowbase * Wn + w0) * Vn + s * 2;
        float2 a = *(const float2*)(mvp);
        float2 c = *(const float2*)(mvp + Vn);
        acc0[0] = a.x; acc0[1] = a.y;
        acc1[0] = c.x; acc1[1] = c.y;
    }

    #pragma unroll 1
    for (int di = 0; di < 5; ++di) {
        const int hh = h + di - 2;
        const bool rowok = (unsigned)hh < (unsigned)Hn;
        const size_t rbase = (size_t)(b * Hn + (rowok ? hh : 0)) * Wn;
        const float* rp = refp + rbase * Cn + s * 8;

        float sc0[5], sc1[5];
        #pragma unroll
        for (int o = 0; o < 6; ++o) {
            const int col = w0 - 2 + o;
            const bool ok = rowok && (unsigned)col < (unsigned)Wn;
            float r[8];
            #pragma unroll
            for (int c = 0; c < 8; ++c) r[c] = 0.f;
            if (ok) load8(r, rp + (size_t)col * Cn);
            if (o < 5) {
                float a = 0.f;
                #pragma unroll
                for (int c = 0; c < 8; ++c) a = fmaf(m0[c], r[c], a);
                sc0[o] = a;
            }
            if (o >= 1) {
                float a = 0.f;
                #pragma unroll
                for (int c = 0; c < 8; ++c) a = fmaf(m1[c], r[c], a);
                sc1[o - 1] = a;
            }
        }
        #pragma unroll
        for (int k = 0; k < 5; ++k) {
            sc0[k] = split_reduce(sc0[k]);
            sc1[k] = split_reduce(sc1[k]);
        }
        const float rm0 = fmaxf(fmaxf(fmaxf(sc0[0], sc0[1]), fmaxf(sc0[2], sc0[3])), sc0[4]);
        const float rm1 = fmaxf(fmaxf(fmaxf(sc1[0], sc1[1]), fmaxf(sc1[2], sc1[3])), sc1[4]);
        const float nm0 = fmaxf(mx0, rm0), nm1 = fmaxf(mx1, rm1);
        const float e0 = __expf(mx0 - nm0), e1 = __expf(mx1 - nm1);
        float sum0 = 0.f, sum1 = 0.f;
        #pragma unroll
        for (int k = 0; k < 5; ++k) {
            sc0[k] = __expf(sc0[k] - nm0); sum0 += sc0[k];
            sc1[k] = __expf(sc1[k] - nm1); sum1 += sc1[k];
        }
        den0 = den0 * e0 + sum0;
        den1 = den1 * e1 + sum1;
        acc0[0] *= e0; acc0[1] *= e0;
        acc1[0] *= e1; acc1[1] *= e1;
        mx0 = nm0; mx1 = nm1;

        const float* rvp = refv + rbase * Vn + s * 2;
        #pragma unroll
        for (int o = 0; o < 6; ++o) {
            const int col = w0 - 2 + o;
            float2 rv = make_float2(0.f, 0.f);
            if (rowok && (unsigned)col < (unsigned)Wn)
                rv = *(const float2*)(rvp + (size_t)col * Vn);
            if (o < 5) {
                const float wkj = sc0[o];
                acc0[0] = fmaf(wkj, rv.x, acc0[0]);
                acc0[1] = fmaf(wkj, rv.y, acc0[1]);
            }
            if (o >= 1) {
                const float wkj = sc1[o - 1];
                acc1[0] = fmaf(wkj, rv.x, acc1[0]);
                acc1[1] = fmaf(wkj, rv.y, acc1[1]);
            }
        }
    }

    const float inv0 = 1.f / den0, inv1 = 1.f / den1;
    float* op = outp + ((size_t)rowbase * Wn + w0) * Vn + s * 2;
    float2 o0, o1;
    o0.x = acc0[0] * inv0; o0.y = acc0[1] * inv0;
    o1.x = acc1[0] * inv1; o1.y = acc1[1] * inv1;
    *(float2*)(op)      = o0;
    *(float2*)(op + Vn) = o1;
}

} // namespace

extern "C" void kernel_launch(void* const* d_in, const int* in_sizes, int n_in,
                              void* d_out, int out_size, void* d_ws, size_t ws_size,
                              hipStream_t stream)
{
    const float* mainp = (const float*)d_in[0];
    const float* mainv = (const float*)d_in[1];
    const float* refp  = (const float*)d_in[2];
    const float* refv  = (const float*)d_in[3];
    float* outp = (float*)d_out;

    if (ws_size < WS_NEED) {
        // workspace too small for fp16 planes: proven VALU path (35.5us)
        hipLaunchKernelGGL(fallback_kernel, dim3(Bn * Hn * 8), dim3(256), 0, stream,
                           mainp, mainv, refp, refv, outp);
        return;
    }

    char* ws = (char*)d_ws;
    _Float16* ahp = (_Float16*)(ws + OFF_AH);
    _Float16* alp = (_Float16*)(ws + OFF_AL);
    _Float16* bhp = (_Float16*)(ws + OFF_BH);
    _Float16* blp = (_Float16*)(ws + OFF_BL);
    _Float16* vtp = (_Float16*)(ws + OFF_VT);

    hipLaunchKernelGGL(prep_split, dim3((unsigned)(N_MAIN / 8 / 256)), dim3(256), 0, stream,
                       mainp, refp, ahp, alp, bhp, blp);
    hipLaunchKernelGGL(prep_vt, dim3((unsigned)(N_VT / 4 / 256)), dim3(256), 0, stream,
                       refv, vtp);
    hipLaunchKernelGGL(attn_mfma, dim3(512), dim3(256), 0, stream,
                       ahp, alp, bhp, blp, vtp, mainv, outp);
}

// Round 19
// 42.597 us; speedup vs baseline: 4.7831x; 4.7831x over previous
//
#include <hip/hip_runtime.h>
#include <math.h>

namespace {

constexpr int Bn = 2, Hn = 128, Wn = 128, Cn = 256, Vn = 64;

__device__ __forceinline__ void load8(float* r, const float* p) {
    float4 a = *(const float4*)(p);
    float4 b = *(const float4*)(p + 4);
    r[0]=a.x; r[1]=a.y; r[2]=a.z; r[3]=a.w;
    r[4]=b.x; r[5]=b.y; r[6]=b.z; r[7]=b.w;
}

// DPP-based add of a row-permuted copy (VALU pipe, not DS). CTRL is a
// compile-time template arg. 0xB1=xor1, 0x4E=xor2, 0x124=row_ror:4,
// 0x128=row_ror:8.
template <int CTRL>
__device__ __forceinline__ float row_add(float v) {
    int sh = __builtin_amdgcn_update_dpp(0, __float_as_int(v), CTRL, 0xF, 0xF, true);
    return v + __int_as_float(sh);
}

// Sum over the 32 split lanes (lane bits 0..4), result in all lanes.
// 4 DPP adds (VALU) + ONE ds_swizzle xor16 (DS) — R12-proven.
__device__ __forceinline__ float split_reduce(float v) {
    v = row_add<0xB1>(v);
    v = row_add<0x4E>(v);
    v = row_add<0x124>(v);
    v = row_add<0x128>(v);
    v += __int_as_float(__builtin_amdgcn_ds_swizzle(__float_as_int(v), 0x401F)); // xor16
    return v;
}

// R12 winner (35.5us: 8 pairs x 32 splits, DPP reduce, online softmax,
// exec-mask predication) with ONE change: di loop unrolled 2x. Evidence:
// all pipes at 40-50% with ~2.6 waves/SIMD resident -> dependent-chain
// latency-bound (VALU ~18us + L1 ~16us ~= 34us serialized = measured dur).
// Unroll-2 gives the scheduler two independent di-chains to interleave
// (di+1 score loads issue under di's softmax). SAFE unlike R18's kk-unroll:
// no register array here is indexed by the loop variable (sc0/sc1 are
// per-iteration locals; m0/m1 static) - rule #20 holds.
__global__ __launch_bounds__(256)
void local_attn_kernel(const float* __restrict__ mainp,
                       const float* __restrict__ mainv,
                       const float* __restrict__ refp,
                       const float* __restrict__ refv,
                       float* __restrict__ outp)
{
    const int t = threadIdx.x;
    const int s = t & 31;       // channel split 0..31 (8 ch each)
    const int g = t >> 5;       // pixel-pair 0..7
    const int blk = blockIdx.x; // 0 .. 2047
    const int seg = blk & 7;
    const int h   = (blk >> 3) & (Hn - 1);
    const int b   = blk >> 10;
    const int w0  = seg * 16 + g * 2;   // px0 = w0, px1 = w0+1
    const int rowbase = b * Hn + h;

    // main channels: 8 each for px0/px1 (ch = s*8 .. s*8+7)
    float m0[8], m1[8];
    const float* mp = mainp + ((size_t)rowbase * Wn + w0) * Cn + s * 8;
    load8(m0, mp);
    load8(m1, mp + Cn);

    // self scores (slot 25)
    float self0 = 0.f, self1 = 0.f;
    #pragma unroll
    for (int c = 0; c < 8; ++c) {
        self0 = fmaf(m0[c], m0[c], self0);
        self1 = fmaf(m1[c], m1[c], self1);
    }
    self0 = split_reduce(self0);
    self1 = split_reduce(self1);

    // online-softmax state seeded with the self slot (weight exp(0)=1)
    float mx0 = self0, mx1 = self1, den0 = 1.f, den1 = 1.f;
    float acc0[2], acc1[2];
    {
        const float* mvp = mainv + ((size_t)rowbase * Wn + w0) * Vn + s * 2;
        float2 a = *(const float2*)(mvp);
        float2 c = *(const float2*)(mvp + Vn);
        acc0[0] = a.x; acc0[1] = a.y;
        acc1[0] = c.x; acc1[1] = c.y;
    }

    #pragma unroll 2
    for (int di = 0; di < 5; ++di) {
        const int hh = h + di - 2;
        const bool rowok = (unsigned)hh < (unsigned)Hn;
        const size_t rbase = (size_t)(b * Hn + (rowok ? hh : 0)) * Wn;
        const float* rp = refp + rbase * Cn + s * 8;

        // ---- scores: 6 shared column loads serve both pixels ----
        float sc0[5], sc1[5];
        #pragma unroll
        for (int o = 0; o < 6; ++o) {
            const int col = w0 - 2 + o;
            const bool ok = rowok && (unsigned)col < (unsigned)Wn;
            float r[8];
            #pragma unroll
            for (int c = 0; c < 8; ++c) r[c] = 0.f;
            if (ok) load8(r, rp + (size_t)col * Cn);
            if (o < 5) {
                float a = 0.f;
                #pragma unroll
                for (int c = 0; c < 8; ++c) a = fmaf(m0[c], r[c], a);
                sc0[o] = a;
            }
            if (o >= 1) {
                float a = 0.f;
                #pragma unroll
                for (int c = 0; c < 8; ++c) a = fmaf(m1[c], r[c], a);
                sc1[o - 1] = a;
            }
        }

        // reduce partial dots across the 32 split lanes
        #pragma unroll
        for (int k = 0; k < 5; ++k) {
            sc0[k] = split_reduce(sc0[k]);
            sc1[k] = split_reduce(sc1[k]);
        }

        // ---- online softmax row update (both pixels)
        const float rm0 = fmaxf(fmaxf(fmaxf(sc0[0], sc0[1]), fmaxf(sc0[2], sc0[3])), sc0[4]);
        const float rm1 = fmaxf(fmaxf(fmaxf(sc1[0], sc1[1]), fmaxf(sc1[2], sc1[3])), sc1[4]);
        const float nm0 = fmaxf(mx0, rm0), nm1 = fmaxf(mx1, rm1);
        const float e0 = __expf(mx0 - nm0), e1 = __expf(mx1 - nm1);
        float sum0 = 0.f, sum1 = 0.f;
        #pragma unroll
        for (int k = 0; k < 5; ++k) {
            sc0[k] = __expf(sc0[k] - nm0); sum0 += sc0[k];
            sc1[k] = __expf(sc1[k] - nm1); sum1 += sc1[k];
        }
        den0 = den0 * e0 + sum0;
        den1 = den1 * e1 + sum1;
        acc0[0] *= e0; acc0[1] *= e0;
        acc1[0] *= e1; acc1[1] *= e1;
        mx0 = nm0; mx1 = nm1;

        // ---- values: 6 shared float2 column loads serve both pixels ----
        const float* rvp = refv + rbase * Vn + s * 2;
        #pragma unroll
        for (int o = 0; o < 6; ++o) {
            const int col = w0 - 2 + o;
            float2 rv = make_float2(0.f, 0.f);
            if (rowok && (unsigned)col < (unsigned)Wn)
                rv = *(const float2*)(rvp + (size_t)col * Vn);
            if (o < 5) {
                const float wkj = sc0[o];
                acc0[0] = fmaf(wkj, rv.x, acc0[0]);
                acc0[1] = fmaf(wkj, rv.y, acc0[1]);
            }
            if (o >= 1) {
                const float wkj = sc1[o - 1];
                acc1[0] = fmaf(wkj, rv.x, acc1[0]);
                acc1[1] = fmaf(wkj, rv.y, acc1[1]);
            }
        }
    }

    const float inv0 = 1.f / den0, inv1 = 1.f / den1;
    float* op = outp + ((size_t)rowbase * Wn + w0) * Vn + s * 2;
    float2 o0, o1;
    o0.x = acc0[0] * inv0; o0.y = acc0[1] * inv0;
    o1.x = acc1[0] * inv1; o1.y = acc1[1] * inv1;
    *(float2*)(op)      = o0;
    *(float2*)(op + Vn) = o1;
}

} // namespace

extern "C" void kernel_launch(void* const* d_in, const int* in_sizes, int n_in,
                              void* d_out, int out_size, void* d_ws, size_t ws_size,
                              hipStream_t stream)
{
    const float* mainp = (const float*)d_in[0];
    const float* mainv = (const float*)d_in[1];
    const float* refp  = (const float*)d_in[2];
    const float* refv  = (const float*)d_in[3];
    float* outp = (float*)d_out;

    dim3 grid(Bn * Hn * 8);   // 2048 blocks: one per 16-pixel row segment
    dim3 block(256);          // 8 pairs x 32 splits
    hipLaunchKernelGGL(local_attn_kernel, grid, block, 0, stream,
                       mainp, mainv, refp, refv, outp);
}

// Round 20
// 35.360 us; speedup vs baseline: 5.7620x; 1.2047x over previous
//
#include <hip/hip_runtime.h>
#include <math.h>

namespace {

constexpr int Bn = 2, Hn = 128, Wn = 128, Cn = 256, Vn = 64;

__device__ __forceinline__ void load8(float* r, const float* p) {
    float4 a = *(const float4*)(p);
    float4 b = *(const float4*)(p + 4);
    r[0]=a.x; r[1]=a.y; r[2]=a.z; r[3]=a.w;
    r[4]=b.x; r[5]=b.y; r[6]=b.z; r[7]=b.w;
}

// DPP-based add of a row-permuted copy (VALU pipe, not DS). CTRL is a
// compile-time template arg. 0xB1=xor1, 0x4E=xor2, 0x124=row_ror:4,
// 0x128=row_ror:8.
template <int CTRL>
__device__ __forceinline__ float row_add(float v) {
    int sh = __builtin_amdgcn_update_dpp(0, __float_as_int(v), CTRL, 0xF, 0xF, true);
    return v + __int_as_float(sh);
}

// Sum over the 32 split lanes (lane bits 0..4), result in all lanes.
// 4 DPP adds (VALU) + ONE ds_swizzle xor16 (DS) — R12-proven.
__device__ __forceinline__ float split_reduce(float v) {
    v = row_add<0xB1>(v);
    v = row_add<0x4E>(v);
    v = row_add<0x124>(v);
    v = row_add<0x128>(v);
    v += __int_as_float(__builtin_amdgcn_ds_swizzle(__float_as_int(v), 0x401F)); // xor16
    return v;
}

// R12 winner (35.5us) with ONE change: VALUE LOADS HOISTED above the
// reduce+softmax chain. Per-di serial chain was score-loads -> reduce ->
// softmax -> value-loads -> value-FMA; the value loads depend only on the
// row base (known at di start), so issuing them right after the score FMAs
// overlaps their ~600cy latency with the reduce/softmax VALU work. Cost is
// +12 VGPR (rv[6]); evidence R4/R12/R19 shows measured residency never hits
// the VGPR-bin cap, so ~70 VGPR should not reduce resident waves.
__global__ __launch_bounds__(256)
void local_attn_kernel(const float* __restrict__ mainp,
                       const float* __restrict__ mainv,
                       const float* __restrict__ refp,
                       const float* __restrict__ refv,
                       float* __restrict__ outp)
{
    const int t = threadIdx.x;
    const int s = t & 31;       // channel split 0..31 (8 ch each)
    const int g = t >> 5;       // pixel-pair 0..7
    const int blk = blockIdx.x; // 0 .. 2047
    const int seg = blk & 7;
    const int h   = (blk >> 3) & (Hn - 1);
    const int b   = blk >> 10;
    const int w0  = seg * 16 + g * 2;   // px0 = w0, px1 = w0+1
    const int rowbase = b * Hn + h;

    // main channels: 8 each for px0/px1 (ch = s*8 .. s*8+7)
    float m0[8], m1[8];
    const float* mp = mainp + ((size_t)rowbase * Wn + w0) * Cn + s * 8;
    load8(m0, mp);
    load8(m1, mp + Cn);

    // self scores (slot 25)
    float self0 = 0.f, self1 = 0.f;
    #pragma unroll
    for (int c = 0; c < 8; ++c) {
        self0 = fmaf(m0[c], m0[c], self0);
        self1 = fmaf(m1[c], m1[c], self1);
    }
    self0 = split_reduce(self0);
    self1 = split_reduce(self1);

    // online-softmax state seeded with the self slot (weight exp(0)=1)
    float mx0 = self0, mx1 = self1, den0 = 1.f, den1 = 1.f;
    float acc0[2], acc1[2];
    {
        const float* mvp = mainv + ((size_t)rowbase * Wn + w0) * Vn + s * 2;
        float2 a = *(const float2*)(mvp);
        float2 c = *(const float2*)(mvp + Vn);
        acc0[0] = a.x; acc0[1] = a.y;
        acc1[0] = c.x; acc1[1] = c.y;
    }

    #pragma unroll 1
    for (int di = 0; di < 5; ++di) {
        const int hh = h + di - 2;
        const bool rowok = (unsigned)hh < (unsigned)Hn;
        const size_t rbase = (size_t)(b * Hn + (rowok ? hh : 0)) * Wn;
        const float* rp = refp + rbase * Cn + s * 8;

        // ---- scores: 6 shared column loads serve both pixels ----
        float sc0[5], sc1[5];
        #pragma unroll
        for (int o = 0; o < 6; ++o) {
            const int col = w0 - 2 + o;
            const bool ok = rowok && (unsigned)col < (unsigned)Wn;
            float r[8];
            #pragma unroll
            for (int c = 0; c < 8; ++c) r[c] = 0.f;
            if (ok) load8(r, rp + (size_t)col * Cn);
            if (o < 5) {
                float a = 0.f;
                #pragma unroll
                for (int c = 0; c < 8; ++c) a = fmaf(m0[c], r[c], a);
                sc0[o] = a;
            }
            if (o >= 1) {
                float a = 0.f;
                #pragma unroll
                for (int c = 0; c < 8; ++c) a = fmaf(m1[c], r[c], a);
                sc1[o - 1] = a;
            }
        }

        // ---- HOISTED value loads: independent of scores; their latency
        //      overlaps the reduce + softmax below ----
        const float* rvp = refv + rbase * Vn + s * 2;
        float2 rv[6];
        #pragma unroll
        for (int o = 0; o < 6; ++o) {
            const int col = w0 - 2 + o;
            rv[o] = make_float2(0.f, 0.f);
            if (rowok && (unsigned)col < (unsigned)Wn)
                rv[o] = *(const float2*)(rvp + (size_t)col * Vn);
        }

        // reduce partial dots across the 32 split lanes
        #pragma unroll
        for (int k = 0; k < 5; ++k) {
            sc0[k] = split_reduce(sc0[k]);
            sc1[k] = split_reduce(sc1[k]);
        }

        // ---- online softmax row update (both pixels)
        const float rm0 = fmaxf(fmaxf(fmaxf(sc0[0], sc0[1]), fmaxf(sc0[2], sc0[3])), sc0[4]);
        const float rm1 = fmaxf(fmaxf(fmaxf(sc1[0], sc1[1]), fmaxf(sc1[2], sc1[3])), sc1[4]);
        const float nm0 = fmaxf(mx0, rm0), nm1 = fmaxf(mx1, rm1);
        const float e0 = __expf(mx0 - nm0), e1 = __expf(mx1 - nm1);
        float sum0 = 0.f, sum1 = 0.f;
        #pragma unroll
        for (int k = 0; k < 5; ++k) {
            sc0[k] = __expf(sc0[k] - nm0); sum0 += sc0[k];
            sc1[k] = __expf(sc1[k] - nm1); sum1 += sc1[k];
        }
        den0 = den0 * e0 + sum0;
        den1 = den1 * e1 + sum1;
        acc0[0] *= e0; acc0[1] *= e0;
        acc1[0] *= e1; acc1[1] *= e1;
        mx0 = nm0; mx1 = nm1;

        // ---- values: FMAs from prefetched rv ----
        #pragma unroll
        for (int o = 0; o < 6; ++o) {
            if (o < 5) {
                const float wkj = sc0[o];
                acc0[0] = fmaf(wkj, rv[o].x, acc0[0]);
                acc0[1] = fmaf(wkj, rv[o].y, acc0[1]);
            }
            if (o >= 1) {
                const float wkj = sc1[o - 1];
                acc1[0] = fmaf(wkj, rv[o].x, acc1[0]);
                acc1[1] = fmaf(wkj, rv[o].y, acc1[1]);
            }
        }
    }

    const float inv0 = 1.f / den0, inv1 = 1.f / den1;
    float* op = outp + ((size_t)rowbase * Wn + w0) * Vn + s * 2;
    float2 o0, o1;
    o0.x = acc0[0] * inv0; o0.y = acc0[1] * inv0;
    o1.x = acc1[0] * inv1; o1.y = acc1[1] * inv1;
    *(float2*)(op)      = o0;
    *(float2*)(op + Vn) = o1;
}

} // namespace

extern "C" void kernel_launch(void* const* d_in, const int* in_sizes, int n_in,
                              void* d_out, int out_size, void* d_ws, size_t ws_size,
                              hipStream_t stream)
{
    const float* mainp = (const float*)d_in[0];
    const float* mainv = (const float*)d_in[1];
    const float* refp  = (const float*)d_in[2];
    const float* refv  = (const float*)d_in[3];
    float* outp = (float*)d_out;

    dim3 grid(Bn * Hn * 8);   // 2048 blocks: one per 16-pixel row segment
    dim3 block(256);          // 8 pairs x 32 splits
    hipLaunchKernelGGL(local_attn_kernel, grid, block, 0, stream,
                       mainp, mainv, refp, refv, outp);
}